// Round 12
// baseline (242.915 us; speedup 1.0000x reference)
//
#include <hip/hip_runtime.h>
#include <hip/hip_cooperative_groups.h>
#include <math.h>

namespace cg = cooperative_groups;

#define T_BINS 350
#define REF_LEN 32
#define NB 32
#define NPIX 3072
#define N1 240
#define N2 10
#define NVAL 256
#define WROW 256                  // padded row width (floats) in W
#define WROWS (NVAL + 1)          // 256 value rows + 1 zero row
#define CH 14                     // chunk length (350 = 25*14)
#define NCHUNK 25
#define GRID_BLOCKS 256           // cooperative grid (1 block/CU guaranteed)

// ---------------------------------------------------------------------------
// Dynamics math (identical constants/ops to all prior rounds).
// ---------------------------------------------------------------------------
#define DYN_CONSTS \
    const double A    = 0.9048374180359595;     \
    const double C    = 0.2718281828459045;     \
    const double Ar   = 0.36787944117144233;    \
    const double Cr   = -54.365636569180904;    \
    const double C31A = 1.0671679036256927e-12; \
    const double C31B = 3.4424771084699765e-14;

#define DYN_CORE(uin)                                         \
        q = A * (q + p);                                      \
        p = A * p + (uin);                                    \
        double vm = C * q + Cr * Q;                           \
        unsigned int sb = (vm >= 10.0) ? 1u : 0u;             \
        double s = (double)sb;                                \
        double sel31 = (hist & 0x80000000u) ? C31A : 0.0;     \
        double sel30 = (hist & 0x40000000u) ? C31B : 0.0;     \
        Q = Ar * (Q + P - sel31);                             \
        P = s + (Ar * P - sel30);                             \
        hist = (hist << 1) | sb;

// expand M(i) for i = 0..13
#define F14(M) M(0) M(1) M(2) M(3) M(4) M(5) M(6) M(7) M(8) M(9) M(10) M(11) M(12) M(13)

// ---------------------------------------------------------------------------
// Single cooperative kernel: 3 former dispatches -> 1 (saves ~2 launch gaps,
// ~10us each per the measured plateau decomposition; grid.sync ~2-3us each).
//   phase 1 = prep      (CSR / w1 transpose / inv map)   [re-indexed to 512]
//   phase 2 = compute_w (one (b,v) per 256-lane half, 16 rounds)
//   phase 3 = fused_dyn (blocks 0..31; BYTE-EXACT R8 body — its internals
//             survived 5 optimization attempts: R7/R8 neutral, R9 +12us,
//             R10 +8us; do not touch)
// All math/order/rounding identical to R11 -> absmax 0.0.
// ---------------------------------------------------------------------------
__global__ __launch_bounds__(512, 1) void snn_all(
        const int* __restrict__ inp,     // [32,3,32,32]
        const int* __restrict__ table,   // [256]
        const float* __restrict__ w1,    // [240,3072]
        const float* __restrict__ w2,    // [10,240]
        float* __restrict__ out,         // [32,10,350]
        float* __restrict__ W,           // [NB][WROWS][WROW]
        float* __restrict__ w1t,         // [NPIX][N1]
        int* __restrict__ pix,           // [NB][NPIX]
        int* __restrict__ offs,          // [NB][NVAL]
        int* __restrict__ cnts,          // [NB][NVAL]
        int* __restrict__ inv)           // [T_BINS]
{
    cg::grid_group grid = cg::this_grid();

    // phase-1 LDS
    __shared__ int lc[NVAL];
    __shared__ int ls[NVAL];
    __shared__ int lslot[NVAL];
    __shared__ float tile[64][65];
    __shared__ int linv[T_BINS];
    // phase-3 LDS
    __shared__ unsigned long long mbuf[2][CH][4];
    __shared__ float u2buf[2][CH][11];
    __shared__ float sout[T_BINS][11];
    __shared__ float lw2[N2][N1 + 1];
    __shared__ int loff[T_BINS];

    const int tid = threadIdx.x;
    const int bx  = blockIdx.x;

    // ======================= phase 1: prep =======================
    if (bx < NB) {
        // ---- CSR build for batch bx (tid<256 guards; uniform barriers) ----
        const int b = bx;
        if (tid < NVAL) lc[tid] = 0;
        __syncthreads();

        int vals[12];
        if (tid < 256) {
            #pragma unroll
            for (int i = 0; i < 12; ++i) {
                int v = inp[b * NPIX + i * 256 + tid];   // coalesced
                vals[i] = v;
                atomicAdd(&lc[v], 1);
            }
        }
        __syncthreads();

        int x = 0;
        if (tid < 256) { x = lc[tid]; ls[tid] = x; }
        __syncthreads();
        for (int d = 1; d < 256; d <<= 1) {
            int y = 0;
            if (tid < 256) y = (tid >= d) ? ls[tid - d] : 0;
            __syncthreads();
            if (tid < 256) ls[tid] += y;
            __syncthreads();
        }
        if (tid < 256) {
            int excl = ls[tid] - x;
            offs[b * NVAL + tid] = excl;
            cnts[b * NVAL + tid] = x;
            lslot[tid] = excl;
        }
        __syncthreads();

        if (tid < 256) {
            #pragma unroll
            for (int i = 0; i < 12; ++i) {
                int slot = atomicAdd(&lslot[vals[i]], 1);
                pix[b * NPIX + slot] = i * 256 + tid;
            }
        }
    } else if (bx < NB + 192) {
        // ---- transpose tile (512 threads: 8 rows/thread) ----
        const int tt = bx - NB;               // 0..191
        const int p0 = (tt % 48) * 64;
        const int n0 = (tt / 48) * 64;
        const int c  = tid & 63;
        const int r0 = tid >> 6;              // 0..7

        #pragma unroll
        for (int i = 0; i < 8; ++i) {
            int row = r0 + i * 8;             // 0..63
            int n = n0 + row;
            if (n < N1) tile[row][c] = w1[n * NPIX + p0 + c];
        }
        __syncthreads();
        #pragma unroll
        for (int i = 0; i < 8; ++i) {
            int row = r0 + i * 8;
            int p = p0 + row;
            int n = n0 + c;
            if (n < N1) w1t[p * N1 + n] = tile[c][row];
        }
    } else if (bx == NB + 192) {
        // ---- inverse bin map ----
        for (int i = tid; i < T_BINS; i += 512) linv[i] = -1;
        __syncthreads();
        if (tid < NVAL) linv[table[tid]] = tid;
        __syncthreads();
        for (int i = tid; i < T_BINS; i += 512) inv[i] = linv[i];
    }

    grid.sync();

    // ======================= phase 2: compute_w =======================
    // zero row (v = NVAL) for empty time bins
    if (bx < NB && tid < 256)
        W[((size_t)bx * WROWS + NVAL) * WROW + tid] = 0.0f;
    {
        const int half = tid >> 8;            // 0/1
        const int col  = tid & 255;
        for (int r = 0; r < 16; ++r) {
            const int task = bx * 32 + half * 16 + r;   // 0..8191
            const int b = task >> 8;
            const int v = task & 255;
            float outv = 0.0f;
            if (col < N1) {
                const int cnt = cnts[b * NVAL + v];
                const int* pl = pix + b * NPIX + offs[b * NVAL + v];
                double acc = 0.0;
                int i = 0;
                for (; i + 4 <= cnt; i += 4) {
                    int p0 = pl[i], p1 = pl[i + 1], p2 = pl[i + 2], p3 = pl[i + 3];
                    double w0  = (double)w1t[p0 * N1 + col];
                    double w1v = (double)w1t[p1 * N1 + col];
                    double w2v = (double)w1t[p2 * N1 + col];
                    double w3  = (double)w1t[p3 * N1 + col];
                    acc += w0; acc += w1v; acc += w2v; acc += w3;  // ascending
                }
                for (; i < cnt; ++i)
                    acc += (double)w1t[pl[i] * N1 + col];
                outv = (float)acc;
            }
            W[((size_t)b * WROWS + v) * WROW + col] = outv;
        }
    }

    grid.sync();

    // ======================= phase 3: fused_dyn (R8 byte-exact) ===========
    if (bx >= NB) return;
    const int b    = bx;
    const int wid  = tid >> 6;
    const int lane = tid & 63;

    for (int i = tid; i < N2 * N1; i += 512) lw2[i / N1][i % N1] = w2[i];
    for (int i = tid; i < T_BINS; i += 512) {
        int v = inv[i];
        loff[i] = ((v >= 0) ? v : NVAL) * (WROW * 4);
    }
    __syncthreads();

    DYN_CONSTS
    double p = 0.0, q = 0.0, P = 0.0, Q = 0.0;   // IIR state: L1 (waves 0-3)
    unsigned int hist = 0u;                       // or L2 (wave 7, lane<10)

#define DECL_CF(i) float c##i = 0.0f, f##i = 0.0f;
    F14(DECL_CF)

    const char* wb = nullptr;
    if (wid < 4) {
        const int n = wid * 64 + lane;            // 0..255, legal (padded) col
        wb = (const char*)W + ((size_t)b * WROWS) * (WROW * 4) + (size_t)n * 4;
#define LOADC(i) c##i = *(const float*)(wb + loff[i]);
        F14(LOADC)
    }

    for (int it = 0; it < NCHUNK + 2; ++it) {
        if (wid < 4 && it < NCHUNK) {
            // ---- stage 1: layer-1 dynamics, chunk it ----
            if (it + 1 < NCHUNK) {
                const int base = (it + 1) * CH;
#define LOADF(i) f##i = *(const float*)(wb + loff[base + i]);
                F14(LOADF)
            }
            const int slot = it & 1;
#define STEP1(i) { DYN_CORE((double)c##i)                                  \
                   unsigned long long msk = __ballot(sb != 0u);            \
                   if (lane == 0) mbuf[slot][i][wid] = msk; }
            F14(STEP1)
            asm volatile("" : "+v"(f0), "+v"(f1), "+v"(f2), "+v"(f3),
                              "+v"(f4), "+v"(f5), "+v"(f6), "+v"(f7),
                              "+v"(f8), "+v"(f9), "+v"(f10), "+v"(f11),
                              "+v"(f12), "+v"(f13));
#define COPYC(i) c##i = f##i;
            F14(COPYC)
        } else if (wid >= 4 && wid < 7 && it >= 1 && it <= NCHUNK) {
            // ---- stage 2: u2 for chunk it-1 (kk asc / ffs asc, verified) ----
            const int item = (wid - 4) * 64 + lane;   // 0..191, need 140
            if (item < CH * N2) {
                const int st = item / N2;
                const int m  = item - st * N2;
                const int slot = (it - 1) & 1;
                double acc = 0.0;
                #pragma unroll
                for (int kk = 0; kk < 4; ++kk) {
                    unsigned long long msk = mbuf[slot][st][kk];
                    while (msk) {
                        int j = __ffsll(msk) - 1;
                        acc += (double)lw2[m][kk * 64 + j];
                        msk &= msk - 1;
                    }
                }
                u2buf[slot][st][m] = (float)acc;
            }
        } else if (wid == 7 && lane < N2 && it >= 2) {
            // ---- stage 3: layer-2 IIR, chunk it-2 ----
            const int cl = it - 2;
            const int slot = cl & 1;
            const int m = lane;
            const int tb = cl * CH;
#define DECL_G(i) float g##i = u2buf[slot][i][m];
            F14(DECL_G)
            asm volatile("" : "+v"(g0), "+v"(g1), "+v"(g2), "+v"(g3),
                              "+v"(g4), "+v"(g5), "+v"(g6), "+v"(g7),
                              "+v"(g8), "+v"(g9), "+v"(g10), "+v"(g11),
                              "+v"(g12), "+v"(g13));
#define STEP3(i) { DYN_CORE((double)g##i) sout[tb + i][m] = (float)s; }
            F14(STEP3)
        }
        __syncthreads();
    }

    // ---- coalesced output out[b][m][t] ----
    float* ob = out + (size_t)b * N2 * T_BINS;
    for (int id = tid; id < N2 * T_BINS; id += 512) {
        const int m = id / T_BINS;
        const int t = id - m * T_BINS;
        ob[id] = sout[t][m];
    }
}

// ---------------------------------------------------------------------------
extern "C" void kernel_launch(void* const* d_in, const int* in_sizes, int n_in,
                              void* d_out, int out_size, void* d_ws, size_t ws_size,
                              hipStream_t stream) {
    const int*   inp   = (const int*)d_in[0];    // [32,3,32,32]
    const int*   table = (const int*)d_in[1];    // [256]
    const float* w1    = (const float*)d_in[2];  // [240,3072]
    const float* w2    = (const float*)d_in[3];  // [10,240]
    float* out = (float*)d_out;                  // [32,10,350]

    char* ws = (char*)d_ws;
    size_t off = 0;
    float* W   = (float*)(ws + off);  off += (size_t)NB * WROWS * WROW * 4;  // 8.4 MB
    float* w1t = (float*)(ws + off);  off += (size_t)NPIX * N1 * 4;          // 2.9 MB
    int*   pix = (int*)(ws + off);    off += (size_t)NB * NPIX * 4;
    int*  offs = (int*)(ws + off);    off += (size_t)NB * NVAL * 4;
    int*  cnts = (int*)(ws + off);    off += (size_t)NB * NVAL * 4;
    int*   inv = (int*)(ws + off);    off += (size_t)T_BINS * 4;

    void* args[] = { (void*)&inp, (void*)&table, (void*)&w1, (void*)&w2,
                     (void*)&out, (void*)&W, (void*)&w1t,
                     (void*)&pix, (void*)&offs, (void*)&cnts, (void*)&inv };
    hipLaunchCooperativeKernel((const void*)snn_all,
                               dim3(GRID_BLOCKS), dim3(512),
                               args, 0, stream);
}

// Round 13
// 165.816 us; speedup vs baseline: 1.4650x; 1.4650x over previous
//
#include <hip/hip_runtime.h>
#include <math.h>

#define T_BINS 350
#define REF_LEN 32
#define NB 32
#define NPIX 3072
#define N1 240
#define N2 10
#define NVAL 256
#define WROW 256                  // padded row width (floats) in W
#define WROWS (NVAL + 1)          // 256 value rows + 1 zero row
#define CH 14                     // chunk length (350 = 25*14)
#define NCHUNK 25

// ---------------------------------------------------------------------------
// Kernel 1 (fused): blocks 0..31 -> per-batch CSR build; blocks 32..223 ->
// 64x64 tiled transpose of w1; block 224 -> inverse bin map inv[t]=v or -1.
// (unchanged, proven)
// ---------------------------------------------------------------------------
__global__ void prep(const int* __restrict__ inp,
                     int* __restrict__ pix,    // [NB][NPIX]
                     int* __restrict__ offs,   // [NB][NVAL]
                     int* __restrict__ cnts,   // [NB][NVAL]
                     const float* __restrict__ w1,
                     float* __restrict__ w1t,
                     const int* __restrict__ table,
                     int* __restrict__ inv)    // [T_BINS]
{
    __shared__ int lc[NVAL];
    __shared__ int ls[NVAL];
    __shared__ int lslot[NVAL];
    __shared__ float tile[64][65];
    __shared__ int linv[T_BINS];

    const int tid = threadIdx.x;

    if (blockIdx.x < NB) {
        // ---- CSR build for batch b ----
        const int b = blockIdx.x;
        lc[tid] = 0;
        __syncthreads();

        int vals[12];
        #pragma unroll
        for (int i = 0; i < 12; ++i) {
            int v = inp[b * NPIX + i * 256 + tid];   // coalesced
            vals[i] = v;
            atomicAdd(&lc[v], 1);
        }
        __syncthreads();

        int x = lc[tid];
        ls[tid] = x;
        __syncthreads();
        for (int d = 1; d < 256; d <<= 1) {
            int y = (tid >= d) ? ls[tid - d] : 0;
            __syncthreads();
            ls[tid] += y;
            __syncthreads();
        }
        int excl = ls[tid] - x;
        offs[b * NVAL + tid] = excl;
        cnts[b * NVAL + tid] = x;
        lslot[tid] = excl;
        __syncthreads();

        #pragma unroll
        for (int i = 0; i < 12; ++i) {
            int slot = atomicAdd(&lslot[vals[i]], 1);
            pix[b * NPIX + slot] = i * 256 + tid;
        }
    } else if (blockIdx.x < NB + 192) {
        // ---- transpose tile ----
        const int tt = blockIdx.x - NB;       // 0..191
        const int p0 = (tt % 48) * 64;
        const int n0 = (tt / 48) * 64;
        const int c  = tid & 63;
        const int r0 = tid >> 6;              // 0..3

        #pragma unroll
        for (int i = 0; i < 16; ++i) {
            int n = n0 + r0 + i * 4;
            if (n < N1) tile[r0 + i * 4][c] = w1[n * NPIX + p0 + c];
        }
        __syncthreads();
        #pragma unroll
        for (int i = 0; i < 16; ++i) {
            int p = p0 + r0 + i * 4;
            int n = n0 + c;
            if (n < N1) w1t[p * N1 + n] = tile[c][r0 + i * 4];
        }
    } else {
        // ---- inverse bin map (table is injective value->bin) ----
        for (int i = tid; i < T_BINS; i += 256) linv[i] = -1;
        __syncthreads();
        if (tid < NVAL) linv[table[tid]] = tid;
        __syncthreads();
        for (int i = tid; i < T_BINS; i += 256) inv[i] = linv[i];
    }
}

// ---------------------------------------------------------------------------
// Kernel 2: W[b][v][n] = sum over pixels with value v of w1t[p, n].
// One value per block (8192 blocks, R11-proven). Padded layout [NB][257][256].
// ---------------------------------------------------------------------------
__global__ void compute_w(const float* __restrict__ w1t,
                          const int* __restrict__ pix,
                          const int* __restrict__ offs,
                          const int* __restrict__ cnts,
                          float* __restrict__ W)     // [NB][WROWS][WROW]
{
    const int v   = blockIdx.x;
    const int b   = blockIdx.y;
    const int tid = threadIdx.x;

    float outv = 0.0f;
    if (tid < N1) {
        const int cnt = cnts[b * NVAL + v];
        const int* pl = pix + b * NPIX + offs[b * NVAL + v];
        double acc = 0.0;
        int i = 0;
        for (; i + 4 <= cnt; i += 4) {
            int p0 = pl[i], p1 = pl[i + 1], p2 = pl[i + 2], p3 = pl[i + 3];
            double w0  = (double)w1t[p0 * N1 + tid];
            double w1v = (double)w1t[p1 * N1 + tid];
            double w2v = (double)w1t[p2 * N1 + tid];
            double w3  = (double)w1t[p3 * N1 + tid];
            acc += w0; acc += w1v; acc += w2v; acc += w3;   // ascending order
        }
        for (; i < cnt; ++i)
            acc += (double)w1t[pl[i] * N1 + tid];
        outv = (float)acc;
    }
    W[((size_t)b * WROWS + v) * WROW + tid] = outv;
    // zero row (v = NVAL) for empty time bins, once per batch
    if (v == 0)
        W[((size_t)b * WROWS + NVAL) * WROW + tid] = 0.0f;
}

// ---------------------------------------------------------------------------
// Dynamics math (identical constants/ops to all prior rounds).
// ---------------------------------------------------------------------------
#define DYN_CONSTS \
    const double A    = 0.9048374180359595;     \
    const double C    = 0.2718281828459045;     \
    const double Ar   = 0.36787944117144233;    \
    const double Cr   = -54.365636569180904;    \
    const double C31A = 1.0671679036256927e-12; \
    const double C31B = 3.4424771084699765e-14;

#define DYN_CORE(uin)                                         \
        q = A * (q + p);                                      \
        p = A * p + (uin);                                    \
        double vm = C * q + Cr * Q;                           \
        unsigned int sb = (vm >= 10.0) ? 1u : 0u;             \
        double s = (double)sb;                                \
        double sel31 = (hist & 0x80000000u) ? C31A : 0.0;     \
        double sel30 = (hist & 0x40000000u) ? C31B : 0.0;     \
        Q = Ar * (Q + P - sel31);                             \
        P = s + (Ar * P - sel30);                             \
        hist = (hist << 1) | sb;

// expand M(i) for i = 0..13
#define F14(M) M(0) M(1) M(2) M(3) M(4) M(5) M(6) M(7) M(8) M(9) M(10) M(11) M(12) M(13)

// ---------------------------------------------------------------------------
// Kernel 3 (pipelined fusion): R8 structure (512 threads = 8 waves; waves
// 0-3 layer-1, 4-6 u2, 7 layer-2; 2-slot LDS pipeline). R13 change is ONLY
// stage 2's inner loop: 4 INDEPENDENT per-word chains, interleaved.
//   Old: one chain, ds_read -> lgkmcnt(0) -> f64 add PER SPIKE (~120cy x
//        ~15 spikes = ~1800 cy/chunk — the measured stage wall per R6:
//        u2l2 56us > layer1 37us, fused = 62 ~ stage-2/3 wall).
//   New: each outer trip walks one bit of each of the 4 words -> up to 4
//        loads in flight, trip count = max word popcount (~1/4 of total).
//   Numerics: within-word add order unchanged; final a0+a1+a2+a3
//   reassociation is safe — the fp32 reference (conv-PSP!) has matched our
//   fp64 pipeline at absmax 0.0 for 12 rounds, so threshold margins are
//   >= fp32 noise (1e-5); reassociation perturbs by <=1e-13.
// ---------------------------------------------------------------------------
__global__ __launch_bounds__(512, 1) void fused_dyn(
        const float* __restrict__ W,     // [NB][WROWS][WROW]
        const int* __restrict__ inv,     // [T_BINS]
        const float* __restrict__ w2,    // [N2][N1]
        float* __restrict__ out)         // [NB][N2][T_BINS]
{
    __shared__ unsigned long long mbuf[2][CH][4];   // 896 B
    __shared__ float u2buf[2][CH][11];              // 1.2 KB (pad 11)
    __shared__ float sout[T_BINS][11];              // 15.4 KB (pad 11)
    __shared__ float lw2[N2][N1 + 1];               // 9.6 KB (pad 241)
    __shared__ int loff[T_BINS];                    // 1.4 KB

    const int tid  = threadIdx.x;
    const int b    = blockIdx.x;
    const int wid  = tid >> 6;
    const int lane = tid & 63;

    for (int i = tid; i < N2 * N1; i += 512) lw2[i / N1][i % N1] = w2[i];
    for (int i = tid; i < T_BINS; i += 512) {
        int v = inv[i];
        loff[i] = ((v >= 0) ? v : NVAL) * (WROW * 4);
    }
    __syncthreads();

    DYN_CONSTS
    double p = 0.0, q = 0.0, P = 0.0, Q = 0.0;   // IIR state: L1 (waves 0-3)
    unsigned int hist = 0u;                       // or L2 (wave 7, lane<10)

    // stage-1 prefetch state: named scalars, never an indexable object
#define DECL_CF(i) float c##i = 0.0f, f##i = 0.0f;
    F14(DECL_CF)

    const char* wb = nullptr;
    if (wid < 4) {
        const int n = wid * 64 + lane;            // 0..255, legal (padded) col
        wb = (const char*)W + ((size_t)b * WROWS) * (WROW * 4) + (size_t)n * 4;
#define LOADC(i) c##i = *(const float*)(wb + loff[i]);
        F14(LOADC)
    }

    for (int it = 0; it < NCHUNK + 2; ++it) {
        if (wid < 4 && it < NCHUNK) {
            // ---- stage 1: layer-1 dynamics, chunk it ----
            if (it + 1 < NCHUNK) {
                const int base = (it + 1) * CH;
#define LOADF(i) f##i = *(const float*)(wb + loff[base + i]);
                F14(LOADF)
            }
            const int slot = it & 1;
#define STEP1(i) { DYN_CORE((double)c##i)                                  \
                   unsigned long long msk = __ballot(sb != 0u);            \
                   if (lane == 0) mbuf[slot][i][wid] = msk; }
            F14(STEP1)
            asm volatile("" : "+v"(f0), "+v"(f1), "+v"(f2), "+v"(f3),
                              "+v"(f4), "+v"(f5), "+v"(f6), "+v"(f7),
                              "+v"(f8), "+v"(f9), "+v"(f10), "+v"(f11),
                              "+v"(f12), "+v"(f13));
#define COPYC(i) c##i = f##i;
            F14(COPYC)
        } else if (wid >= 4 && wid < 7 && it >= 1 && it <= NCHUNK) {
            // ---- stage 2: u2 for chunk it-1; 4 interleaved word-chains ----
            const int item = (wid - 4) * 64 + lane;   // 0..191, need 140
            if (item < CH * N2) {
                const int st = item / N2;
                const int m  = item - st * N2;
                const int slot = (it - 1) & 1;
                unsigned long long m0 = mbuf[slot][st][0];
                unsigned long long m1 = mbuf[slot][st][1];
                unsigned long long m2 = mbuf[slot][st][2];
                unsigned long long m3 = mbuf[slot][st][3];
                const float* wr = &lw2[m][0];
                double a0 = 0.0, a1 = 0.0, a2 = 0.0, a3 = 0.0;
                while (m0 | m1 | m2 | m3) {
                    if (m0) { int j = __ffsll(m0) - 1; a0 += (double)wr[j];       m0 &= m0 - 1; }
                    if (m1) { int j = __ffsll(m1) - 1; a1 += (double)wr[64 + j];  m1 &= m1 - 1; }
                    if (m2) { int j = __ffsll(m2) - 1; a2 += (double)wr[128 + j]; m2 &= m2 - 1; }
                    if (m3) { int j = __ffsll(m3) - 1; a3 += (double)wr[192 + j]; m3 &= m3 - 1; }
                }
                double acc = a0; acc += a1; acc += a2; acc += a3;
                u2buf[slot][st][m] = (float)acc;
            }
        } else if (wid == 7 && lane < N2 && it >= 2) {
            // ---- stage 3: layer-2 IIR, chunk it-2 ----
            const int cl = it - 2;
            const int slot = cl & 1;
            const int m = lane;
            const int tb = cl * CH;
#define DECL_G(i) float g##i = u2buf[slot][i][m];
            F14(DECL_G)
            asm volatile("" : "+v"(g0), "+v"(g1), "+v"(g2), "+v"(g3),
                              "+v"(g4), "+v"(g5), "+v"(g6), "+v"(g7),
                              "+v"(g8), "+v"(g9), "+v"(g10), "+v"(g11),
                              "+v"(g12), "+v"(g13));
#define STEP3(i) { DYN_CORE((double)g##i) sout[tb + i][m] = (float)s; }
            F14(STEP3)
        }
        __syncthreads();
    }

    // ---- coalesced output out[b][m][t] ----
    float* ob = out + (size_t)b * N2 * T_BINS;
    for (int id = tid; id < N2 * T_BINS; id += 512) {
        const int m = id / T_BINS;
        const int t = id - m * T_BINS;
        ob[id] = sout[t][m];
    }
}

// ---------------------------------------------------------------------------
extern "C" void kernel_launch(void* const* d_in, const int* in_sizes, int n_in,
                              void* d_out, int out_size, void* d_ws, size_t ws_size,
                              hipStream_t stream) {
    const int*   inp   = (const int*)d_in[0];    // [32,3,32,32]
    const int*   table = (const int*)d_in[1];    // [256]
    const float* w1    = (const float*)d_in[2];  // [240,3072]
    const float* w2    = (const float*)d_in[3];  // [10,240]
    float* out = (float*)d_out;                  // [32,10,350]

    char* ws = (char*)d_ws;
    size_t off = 0;
    float* W   = (float*)(ws + off);  off += (size_t)NB * WROWS * WROW * 4;  // 8.4 MB
    float* w1t = (float*)(ws + off);  off += (size_t)NPIX * N1 * 4;          // 2.9 MB
    int*   pix = (int*)(ws + off);    off += (size_t)NB * NPIX * 4;
    int*  offs = (int*)(ws + off);    off += (size_t)NB * NVAL * 4;
    int*  cnts = (int*)(ws + off);    off += (size_t)NB * NVAL * 4;
    int*   inv = (int*)(ws + off);    off += (size_t)T_BINS * 4;

    prep<<<NB + 192 + 1, 256, 0, stream>>>(inp, pix, offs, cnts, w1, w1t, table, inv);
    compute_w<<<dim3(NVAL, NB), 256, 0, stream>>>(w1t, pix, offs, cnts, W);
    fused_dyn<<<NB, 512, 0, stream>>>(W, inv, w2, out);
}

// Round 14
// 143.476 us; speedup vs baseline: 1.6931x; 1.1557x over previous
//
#include <hip/hip_runtime.h>
#include <math.h>

#define T_BINS 350
#define REF_LEN 32
#define NB 32
#define NPIX 3072
#define N1 240
#define N2 10
#define NVAL 256
#define WROW 256                  // padded row width (floats) in W
#define WROWS (NVAL + 1)          // 256 value rows + 1 zero row
#define CH 14                     // chunk length (350 = 25*14)
#define NCHUNK 25

// ---------------------------------------------------------------------------
// Kernel 1 (fused): blocks 0..31 -> per-batch CSR build; blocks 32..223 ->
// 64x64 tiled transpose of w1; block 224 -> inverse bin map inv[t]=v or -1.
// (unchanged, proven)
// ---------------------------------------------------------------------------
__global__ void prep(const int* __restrict__ inp,
                     int* __restrict__ pix,    // [NB][NPIX]
                     int* __restrict__ offs,   // [NB][NVAL]
                     int* __restrict__ cnts,   // [NB][NVAL]
                     const float* __restrict__ w1,
                     float* __restrict__ w1t,
                     const int* __restrict__ table,
                     int* __restrict__ inv)    // [T_BINS]
{
    __shared__ int lc[NVAL];
    __shared__ int ls[NVAL];
    __shared__ int lslot[NVAL];
    __shared__ float tile[64][65];
    __shared__ int linv[T_BINS];

    const int tid = threadIdx.x;

    if (blockIdx.x < NB) {
        // ---- CSR build for batch b ----
        const int b = blockIdx.x;
        lc[tid] = 0;
        __syncthreads();

        int vals[12];
        #pragma unroll
        for (int i = 0; i < 12; ++i) {
            int v = inp[b * NPIX + i * 256 + tid];   // coalesced
            vals[i] = v;
            atomicAdd(&lc[v], 1);
        }
        __syncthreads();

        int x = lc[tid];
        ls[tid] = x;
        __syncthreads();
        for (int d = 1; d < 256; d <<= 1) {
            int y = (tid >= d) ? ls[tid - d] : 0;
            __syncthreads();
            ls[tid] += y;
            __syncthreads();
        }
        int excl = ls[tid] - x;
        offs[b * NVAL + tid] = excl;
        cnts[b * NVAL + tid] = x;
        lslot[tid] = excl;
        __syncthreads();

        #pragma unroll
        for (int i = 0; i < 12; ++i) {
            int slot = atomicAdd(&lslot[vals[i]], 1);
            pix[b * NPIX + slot] = i * 256 + tid;
        }
    } else if (blockIdx.x < NB + 192) {
        // ---- transpose tile ----
        const int tt = blockIdx.x - NB;       // 0..191
        const int p0 = (tt % 48) * 64;
        const int n0 = (tt / 48) * 64;
        const int c  = tid & 63;
        const int r0 = tid >> 6;              // 0..3

        #pragma unroll
        for (int i = 0; i < 16; ++i) {
            int n = n0 + r0 + i * 4;
            if (n < N1) tile[r0 + i * 4][c] = w1[n * NPIX + p0 + c];
        }
        __syncthreads();
        #pragma unroll
        for (int i = 0; i < 16; ++i) {
            int p = p0 + r0 + i * 4;
            int n = n0 + c;
            if (n < N1) w1t[p * N1 + n] = tile[c][r0 + i * 4];
        }
    } else {
        // ---- inverse bin map (table is injective value->bin) ----
        for (int i = tid; i < T_BINS; i += 256) linv[i] = -1;
        __syncthreads();
        if (tid < NVAL) linv[table[tid]] = tid;
        __syncthreads();
        for (int i = tid; i < T_BINS; i += 256) inv[i] = linv[i];
    }
}

// ---------------------------------------------------------------------------
// Kernel 2: W[b][v][n] = sum over pixels with value v of w1t[p, n].
// One value per block (8192 blocks, R11-proven). Padded layout [NB][257][256].
// ---------------------------------------------------------------------------
__global__ void compute_w(const float* __restrict__ w1t,
                          const int* __restrict__ pix,
                          const int* __restrict__ offs,
                          const int* __restrict__ cnts,
                          float* __restrict__ W)     // [NB][WROWS][WROW]
{
    const int v   = blockIdx.x;
    const int b   = blockIdx.y;
    const int tid = threadIdx.x;

    float outv = 0.0f;
    if (tid < N1) {
        const int cnt = cnts[b * NVAL + v];
        const int* pl = pix + b * NPIX + offs[b * NVAL + v];
        double acc = 0.0;
        int i = 0;
        for (; i + 4 <= cnt; i += 4) {
            int p0 = pl[i], p1 = pl[i + 1], p2 = pl[i + 2], p3 = pl[i + 3];
            double w0  = (double)w1t[p0 * N1 + tid];
            double w1v = (double)w1t[p1 * N1 + tid];
            double w2v = (double)w1t[p2 * N1 + tid];
            double w3  = (double)w1t[p3 * N1 + tid];
            acc += w0; acc += w1v; acc += w2v; acc += w3;   // ascending order
        }
        for (; i < cnt; ++i)
            acc += (double)w1t[pl[i] * N1 + tid];
        outv = (float)acc;
    }
    W[((size_t)b * WROWS + v) * WROW + tid] = outv;
    // zero row (v = NVAL) for empty time bins, once per batch
    if (v == 0)
        W[((size_t)b * WROWS + NVAL) * WROW + tid] = 0.0f;
}

// ---------------------------------------------------------------------------
// Dynamics math (identical constants/ops to all prior rounds).
// ---------------------------------------------------------------------------
#define DYN_CONSTS \
    const double A    = 0.9048374180359595;     \
    const double C    = 0.2718281828459045;     \
    const double Ar   = 0.36787944117144233;    \
    const double Cr   = -54.365636569180904;    \
    const double C31A = 1.0671679036256927e-12; \
    const double C31B = 3.4424771084699765e-14;

#define DYN_CORE(uin)                                         \
        q = A * (q + p);                                      \
        p = A * p + (uin);                                    \
        double vm = C * q + Cr * Q;                           \
        unsigned int sb = (vm >= 10.0) ? 1u : 0u;             \
        double s = (double)sb;                                \
        double sel31 = (hist & 0x80000000u) ? C31A : 0.0;     \
        double sel30 = (hist & 0x40000000u) ? C31B : 0.0;     \
        Q = Ar * (Q + P - sel31);                             \
        P = s + (Ar * P - sel30);                             \
        hist = (hist << 1) | sb;

// expand M(i) for i = 0..13
#define F14(M) M(0) M(1) M(2) M(3) M(4) M(5) M(6) M(7) M(8) M(9) M(10) M(11) M(12) M(13)

// ---------------------------------------------------------------------------
// Kernel 3 (pipelined fusion): EXACT R8/R11 version — best measured (62.1us,
// reproduced twice). Defense record of this structure (do not modify):
//   R7/R8 stage-1 codegen: neutral | R9 stage-2 4-wide ILP: +12us
//   R10 stage-2 9-wave split: +8us | R12 coop fusion: +104us
//   R13 stage-2 interleaved chains: +29us
// 512 threads = 8 waves: 0-3 layer-1 (named-scalar float prefetch,
// unconditional padded-W loads), 4-6 u2 bit-walk (tight 3-instr body),
// 7 layer-2. 2-slot LDS pipeline, one barrier per chunk.
// ---------------------------------------------------------------------------
__global__ __launch_bounds__(512, 1) void fused_dyn(
        const float* __restrict__ W,     // [NB][WROWS][WROW]
        const int* __restrict__ inv,     // [T_BINS]
        const float* __restrict__ w2,    // [N2][N1]
        float* __restrict__ out)         // [NB][N2][T_BINS]
{
    __shared__ unsigned long long mbuf[2][CH][4];   // 896 B
    __shared__ float u2buf[2][CH][11];              // 1.2 KB (pad 11)
    __shared__ float sout[T_BINS][11];              // 15.4 KB (pad 11)
    __shared__ float lw2[N2][N1 + 1];               // 9.6 KB (pad 241)
    __shared__ int loff[T_BINS];                    // 1.4 KB

    const int tid  = threadIdx.x;
    const int b    = blockIdx.x;
    const int wid  = tid >> 6;
    const int lane = tid & 63;

    for (int i = tid; i < N2 * N1; i += 512) lw2[i / N1][i % N1] = w2[i];
    for (int i = tid; i < T_BINS; i += 512) {
        int v = inv[i];
        loff[i] = ((v >= 0) ? v : NVAL) * (WROW * 4);
    }
    __syncthreads();

    DYN_CONSTS
    double p = 0.0, q = 0.0, P = 0.0, Q = 0.0;   // IIR state: L1 (waves 0-3)
    unsigned int hist = 0u;                       // or L2 (wave 7, lane<10)

    // stage-1 prefetch state: named scalars, never an indexable object
#define DECL_CF(i) float c##i = 0.0f, f##i = 0.0f;
    F14(DECL_CF)

    const char* wb = nullptr;
    if (wid < 4) {
        const int n = wid * 64 + lane;            // 0..255, legal (padded) col
        wb = (const char*)W + ((size_t)b * WROWS) * (WROW * 4) + (size_t)n * 4;
#define LOADC(i) c##i = *(const float*)(wb + loff[i]);
        F14(LOADC)
    }

    for (int it = 0; it < NCHUNK + 2; ++it) {
        if (wid < 4 && it < NCHUNK) {
            // ---- stage 1: layer-1 dynamics, chunk it ----
            if (it + 1 < NCHUNK) {
                const int base = (it + 1) * CH;
#define LOADF(i) f##i = *(const float*)(wb + loff[base + i]);
                F14(LOADF)
            }
            const int slot = it & 1;
#define STEP1(i) { DYN_CORE((double)c##i)                                  \
                   unsigned long long msk = __ballot(sb != 0u);            \
                   if (lane == 0) mbuf[slot][i][wid] = msk; }
            F14(STEP1)
            asm volatile("" : "+v"(f0), "+v"(f1), "+v"(f2), "+v"(f3),
                              "+v"(f4), "+v"(f5), "+v"(f6), "+v"(f7),
                              "+v"(f8), "+v"(f9), "+v"(f10), "+v"(f11),
                              "+v"(f12), "+v"(f13));
#define COPYC(i) c##i = f##i;
            F14(COPYC)
        } else if (wid >= 4 && wid < 7 && it >= 1 && it <= NCHUNK) {
            // ---- stage 2: u2 for chunk it-1 (kk asc / ffs asc, verified) ----
            const int item = (wid - 4) * 64 + lane;   // 0..191, need 140
            if (item < CH * N2) {
                const int st = item / N2;
                const int m  = item - st * N2;
                const int slot = (it - 1) & 1;
                double acc = 0.0;
                #pragma unroll
                for (int kk = 0; kk < 4; ++kk) {
                    unsigned long long msk = mbuf[slot][st][kk];
                    while (msk) {
                        int j = __ffsll(msk) - 1;
                        acc += (double)lw2[m][kk * 64 + j];
                        msk &= msk - 1;
                    }
                }
                u2buf[slot][st][m] = (float)acc;
            }
        } else if (wid == 7 && lane < N2 && it >= 2) {
            // ---- stage 3: layer-2 IIR, chunk it-2 ----
            const int cl = it - 2;
            const int slot = cl & 1;
            const int m = lane;
            const int tb = cl * CH;
#define DECL_G(i) float g##i = u2buf[slot][i][m];
            F14(DECL_G)
            asm volatile("" : "+v"(g0), "+v"(g1), "+v"(g2), "+v"(g3),
                              "+v"(g4), "+v"(g5), "+v"(g6), "+v"(g7),
                              "+v"(g8), "+v"(g9), "+v"(g10), "+v"(g11),
                              "+v"(g12), "+v"(g13));
#define STEP3(i) { DYN_CORE((double)g##i) sout[tb + i][m] = (float)s; }
            F14(STEP3)
        }
        __syncthreads();
    }

    // ---- coalesced output out[b][m][t] ----
    float* ob = out + (size_t)b * N2 * T_BINS;
    for (int id = tid; id < N2 * T_BINS; id += 512) {
        const int m = id / T_BINS;
        const int t = id - m * T_BINS;
        ob[id] = sout[t][m];
    }
}

// ---------------------------------------------------------------------------
extern "C" void kernel_launch(void* const* d_in, const int* in_sizes, int n_in,
                              void* d_out, int out_size, void* d_ws, size_t ws_size,
                              hipStream_t stream) {
    const int*   inp   = (const int*)d_in[0];    // [32,3,32,32]
    const int*   table = (const int*)d_in[1];    // [256]
    const float* w1    = (const float*)d_in[2];  // [240,3072]
    const float* w2    = (const float*)d_in[3];  // [10,240]
    float* out = (float*)d_out;                  // [32,10,350]

    char* ws = (char*)d_ws;
    size_t off = 0;
    float* W   = (float*)(ws + off);  off += (size_t)NB * WROWS * WROW * 4;  // 8.4 MB
    float* w1t = (float*)(ws + off);  off += (size_t)NPIX * N1 * 4;          // 2.9 MB
    int*   pix = (int*)(ws + off);    off += (size_t)NB * NPIX * 4;
    int*  offs = (int*)(ws + off);    off += (size_t)NB * NVAL * 4;
    int*  cnts = (int*)(ws + off);    off += (size_t)NB * NVAL * 4;
    int*   inv = (int*)(ws + off);    off += (size_t)T_BINS * 4;

    prep<<<NB + 192 + 1, 256, 0, stream>>>(inp, pix, offs, cnts, w1, w1t, table, inv);
    compute_w<<<dim3(NVAL, NB), 256, 0, stream>>>(w1t, pix, offs, cnts, W);
    fused_dyn<<<NB, 512, 0, stream>>>(W, inv, w2, out);
}

// Round 15
// 129.433 us; speedup vs baseline: 1.8768x; 1.1085x over previous
//
#include <hip/hip_runtime.h>
#include <math.h>

#define T_BINS 350
#define REF_LEN 32
#define NB 32
#define NPIX 3072
#define N1 240
#define N2 10
#define NVAL 256
#define WROW 256                  // padded row width (floats) in W
#define WROWS (NVAL + 1)          // 256 value rows + 1 zero row
#define CH 25                     // chunk length (350 = 14*25)  [R15: was 14]
#define NCHUNK 14
#define NTHREADS 576              // 9 waves: 4 L1 + 4 u2 + 1 L2

// ---------------------------------------------------------------------------
// Kernel 1 (fused): blocks 0..31 -> per-batch CSR build; blocks 32..223 ->
// 64x64 tiled transpose of w1; block 224 -> inverse bin map inv[t]=v or -1.
// (unchanged, proven)
// ---------------------------------------------------------------------------
__global__ void prep(const int* __restrict__ inp,
                     int* __restrict__ pix,    // [NB][NPIX]
                     int* __restrict__ offs,   // [NB][NVAL]
                     int* __restrict__ cnts,   // [NB][NVAL]
                     const float* __restrict__ w1,
                     float* __restrict__ w1t,
                     const int* __restrict__ table,
                     int* __restrict__ inv)    // [T_BINS]
{
    __shared__ int lc[NVAL];
    __shared__ int ls[NVAL];
    __shared__ int lslot[NVAL];
    __shared__ float tile[64][65];
    __shared__ int linv[T_BINS];

    const int tid = threadIdx.x;

    if (blockIdx.x < NB) {
        // ---- CSR build for batch b ----
        const int b = blockIdx.x;
        lc[tid] = 0;
        __syncthreads();

        int vals[12];
        #pragma unroll
        for (int i = 0; i < 12; ++i) {
            int v = inp[b * NPIX + i * 256 + tid];   // coalesced
            vals[i] = v;
            atomicAdd(&lc[v], 1);
        }
        __syncthreads();

        int x = lc[tid];
        ls[tid] = x;
        __syncthreads();
        for (int d = 1; d < 256; d <<= 1) {
            int y = (tid >= d) ? ls[tid - d] : 0;
            __syncthreads();
            ls[tid] += y;
            __syncthreads();
        }
        int excl = ls[tid] - x;
        offs[b * NVAL + tid] = excl;
        cnts[b * NVAL + tid] = x;
        lslot[tid] = excl;
        __syncthreads();

        #pragma unroll
        for (int i = 0; i < 12; ++i) {
            int slot = atomicAdd(&lslot[vals[i]], 1);
            pix[b * NPIX + slot] = i * 256 + tid;
        }
    } else if (blockIdx.x < NB + 192) {
        // ---- transpose tile ----
        const int tt = blockIdx.x - NB;       // 0..191
        const int p0 = (tt % 48) * 64;
        const int n0 = (tt / 48) * 64;
        const int c  = tid & 63;
        const int r0 = tid >> 6;              // 0..3

        #pragma unroll
        for (int i = 0; i < 16; ++i) {
            int n = n0 + r0 + i * 4;
            if (n < N1) tile[r0 + i * 4][c] = w1[n * NPIX + p0 + c];
        }
        __syncthreads();
        #pragma unroll
        for (int i = 0; i < 16; ++i) {
            int p = p0 + r0 + i * 4;
            int n = n0 + c;
            if (n < N1) w1t[p * N1 + n] = tile[c][r0 + i * 4];
        }
    } else {
        // ---- inverse bin map (table is injective value->bin) ----
        for (int i = tid; i < T_BINS; i += 256) linv[i] = -1;
        __syncthreads();
        if (tid < NVAL) linv[table[tid]] = tid;
        __syncthreads();
        for (int i = tid; i < T_BINS; i += 256) inv[i] = linv[i];
    }
}

// ---------------------------------------------------------------------------
// Kernel 2: W[b][v][n] = sum over pixels with value v of w1t[p, n].
// One value per block (8192 blocks, R11-proven). Padded layout [NB][257][256].
// ---------------------------------------------------------------------------
__global__ void compute_w(const float* __restrict__ w1t,
                          const int* __restrict__ pix,
                          const int* __restrict__ offs,
                          const int* __restrict__ cnts,
                          float* __restrict__ W)     // [NB][WROWS][WROW]
{
    const int v   = blockIdx.x;
    const int b   = blockIdx.y;
    const int tid = threadIdx.x;

    float outv = 0.0f;
    if (tid < N1) {
        const int cnt = cnts[b * NVAL + v];
        const int* pl = pix + b * NPIX + offs[b * NVAL + v];
        double acc = 0.0;
        int i = 0;
        for (; i + 4 <= cnt; i += 4) {
            int p0 = pl[i], p1 = pl[i + 1], p2 = pl[i + 2], p3 = pl[i + 3];
            double w0  = (double)w1t[p0 * N1 + tid];
            double w1v = (double)w1t[p1 * N1 + tid];
            double w2v = (double)w1t[p2 * N1 + tid];
            double w3  = (double)w1t[p3 * N1 + tid];
            acc += w0; acc += w1v; acc += w2v; acc += w3;   // ascending order
        }
        for (; i < cnt; ++i)
            acc += (double)w1t[pl[i] * N1 + tid];
        outv = (float)acc;
    }
    W[((size_t)b * WROWS + v) * WROW + tid] = outv;
    // zero row (v = NVAL) for empty time bins, once per batch
    if (v == 0)
        W[((size_t)b * WROWS + NVAL) * WROW + tid] = 0.0f;
}

// ---------------------------------------------------------------------------
// Dynamics math (identical constants/ops to all prior rounds).
// ---------------------------------------------------------------------------
#define DYN_CONSTS \
    const double A    = 0.9048374180359595;     \
    const double C    = 0.2718281828459045;     \
    const double Ar   = 0.36787944117144233;    \
    const double Cr   = -54.365636569180904;    \
    const double C31A = 1.0671679036256927e-12; \
    const double C31B = 3.4424771084699765e-14;

#define DYN_CORE(uin)                                         \
        q = A * (q + p);                                      \
        p = A * p + (uin);                                    \
        double vm = C * q + Cr * Q;                           \
        unsigned int sb = (vm >= 10.0) ? 1u : 0u;             \
        double s = (double)sb;                                \
        double sel31 = (hist & 0x80000000u) ? C31A : 0.0;     \
        double sel30 = (hist & 0x40000000u) ? C31B : 0.0;     \
        Q = Ar * (Q + P - sel31);                             \
        P = s + (Ar * P - sel30);                             \
        hist = (hist << 1) | sb;

// expand M(i) for i = 0..24
#define F25(M) M(0) M(1) M(2) M(3) M(4) M(5) M(6) M(7) M(8) M(9) M(10) M(11) \
               M(12) M(13) M(14) M(15) M(16) M(17) M(18) M(19) M(20) M(21)   \
               M(22) M(23) M(24)

// ---------------------------------------------------------------------------
// Kernel 3 (pipelined fusion). R15: ONLY structural parameter changed vs the
// six-times-defended R8/R11 kernel — CH 14->25, i.e. pipeline iterations
// 27->16. Rationale: every failed intervention (R9/R10/R13 stage
// redistribution, R7/R8 codegen, R12 coop) varied WORK DISTRIBUTION; none
// varied the per-iteration fixed cost count. R10's key datum (stage-2 work
// /4 per lane yet time UP with +6 waves) says time/chunk = large fixed
// convoy term + body. Fewer, fatter chunks amortize the fixed term.
// 9 waves (576 thr): 0-3 layer-1 (named-scalar float prefetch, 25-deep),
// 4-7 u2 (250 items, one per lane), 8 layer-2. Same 2-slot LDS pipeline,
// same per-element math/order/rounding -> absmax 0.0.
// ---------------------------------------------------------------------------
__global__ __launch_bounds__(NTHREADS, 1) void fused_dyn(
        const float* __restrict__ W,     // [NB][WROWS][WROW]
        const int* __restrict__ inv,     // [T_BINS]
        const float* __restrict__ w2,    // [N2][N1]
        float* __restrict__ out)         // [NB][N2][T_BINS]
{
    __shared__ unsigned long long mbuf[2][CH][4];   // 1.6 KB
    __shared__ float u2buf[2][CH][11];              // 2.2 KB (pad 11)
    __shared__ float sout[T_BINS][11];              // 15.4 KB (pad 11)
    __shared__ float lw2[N2][N1 + 1];               // 9.6 KB (pad 241)
    __shared__ int loff[T_BINS];                    // 1.4 KB

    const int tid  = threadIdx.x;
    const int b    = blockIdx.x;
    const int wid  = tid >> 6;
    const int lane = tid & 63;

    for (int i = tid; i < N2 * N1; i += NTHREADS) lw2[i / N1][i % N1] = w2[i];
    for (int i = tid; i < T_BINS; i += NTHREADS) {
        int v = inv[i];
        loff[i] = ((v >= 0) ? v : NVAL) * (WROW * 4);
    }
    __syncthreads();

    DYN_CONSTS
    double p = 0.0, q = 0.0, P = 0.0, Q = 0.0;   // IIR state: L1 (waves 0-3)
    unsigned int hist = 0u;                       // or L2 (wave 8, lane<10)

    // stage-1 prefetch state: named scalars, never an indexable object
#define DECL_CF(i) float c##i = 0.0f, f##i = 0.0f;
    F25(DECL_CF)

    const char* wb = nullptr;
    if (wid < 4) {
        const int n = wid * 64 + lane;            // 0..255, legal (padded) col
        wb = (const char*)W + ((size_t)b * WROWS) * (WROW * 4) + (size_t)n * 4;
#define LOADC(i) c##i = *(const float*)(wb + loff[i]);
        F25(LOADC)
    }

    for (int it = 0; it < NCHUNK + 2; ++it) {
        if (wid < 4 && it < NCHUNK) {
            // ---- stage 1: layer-1 dynamics, chunk it ----
            if (it + 1 < NCHUNK) {
                const int base = (it + 1) * CH;
#define LOADF(i) f##i = *(const float*)(wb + loff[base + i]);
                F25(LOADF)
            }
            const int slot = it & 1;
#define STEP1(i) { DYN_CORE((double)c##i)                                  \
                   unsigned long long msk = __ballot(sb != 0u);            \
                   if (lane == 0) mbuf[slot][i][wid] = msk; }
            F25(STEP1)
            asm volatile("" : "+v"(f0), "+v"(f1), "+v"(f2), "+v"(f3),
                              "+v"(f4), "+v"(f5), "+v"(f6), "+v"(f7),
                              "+v"(f8), "+v"(f9), "+v"(f10), "+v"(f11),
                              "+v"(f12));
            asm volatile("" : "+v"(f13), "+v"(f14), "+v"(f15), "+v"(f16),
                              "+v"(f17), "+v"(f18), "+v"(f19), "+v"(f20),
                              "+v"(f21), "+v"(f22), "+v"(f23), "+v"(f24));
#define COPYC(i) c##i = f##i;
            F25(COPYC)
        } else if (wid >= 4 && wid < 8 && it >= 1 && it <= NCHUNK) {
            // ---- stage 2: u2 for chunk it-1 (kk asc / ffs asc, verified) ----
            const int item = (wid - 4) * 64 + lane;   // 0..255, need 250
            if (item < CH * N2) {
                const int st = item / N2;
                const int m  = item - st * N2;
                const int slot = (it - 1) & 1;
                double acc = 0.0;
                #pragma unroll
                for (int kk = 0; kk < 4; ++kk) {
                    unsigned long long msk = mbuf[slot][st][kk];
                    while (msk) {
                        int j = __ffsll(msk) - 1;
                        acc += (double)lw2[m][kk * 64 + j];
                        msk &= msk - 1;
                    }
                }
                u2buf[slot][st][m] = (float)acc;
            }
        } else if (wid == 8 && lane < N2 && it >= 2) {
            // ---- stage 3: layer-2 IIR, chunk it-2 ----
            const int cl = it - 2;
            const int slot = cl & 1;
            const int m = lane;
            const int tb = cl * CH;
#define DECL_G(i) float g##i = u2buf[slot][i][m];
            F25(DECL_G)
            asm volatile("" : "+v"(g0), "+v"(g1), "+v"(g2), "+v"(g3),
                              "+v"(g4), "+v"(g5), "+v"(g6), "+v"(g7),
                              "+v"(g8), "+v"(g9), "+v"(g10), "+v"(g11),
                              "+v"(g12));
            asm volatile("" : "+v"(g13), "+v"(g14), "+v"(g15), "+v"(g16),
                              "+v"(g17), "+v"(g18), "+v"(g19), "+v"(g20),
                              "+v"(g21), "+v"(g22), "+v"(g23), "+v"(g24));
#define STEP3(i) { DYN_CORE((double)g##i) sout[tb + i][m] = (float)s; }
            F25(STEP3)
        }
        __syncthreads();
    }

    // ---- coalesced output out[b][m][t] ----
    float* ob = out + (size_t)b * N2 * T_BINS;
    for (int id = tid; id < N2 * T_BINS; id += NTHREADS) {
        const int m = id / T_BINS;
        const int t = id - m * T_BINS;
        ob[id] = sout[t][m];
    }
}

// ---------------------------------------------------------------------------
extern "C" void kernel_launch(void* const* d_in, const int* in_sizes, int n_in,
                              void* d_out, int out_size, void* d_ws, size_t ws_size,
                              hipStream_t stream) {
    const int*   inp   = (const int*)d_in[0];    // [32,3,32,32]
    const int*   table = (const int*)d_in[1];    // [256]
    const float* w1    = (const float*)d_in[2];  // [240,3072]
    const float* w2    = (const float*)d_in[3];  // [10,240]
    float* out = (float*)d_out;                  // [32,10,350]

    char* ws = (char*)d_ws;
    size_t off = 0;
    float* W   = (float*)(ws + off);  off += (size_t)NB * WROWS * WROW * 4;  // 8.4 MB
    float* w1t = (float*)(ws + off);  off += (size_t)NPIX * N1 * 4;          // 2.9 MB
    int*   pix = (int*)(ws + off);    off += (size_t)NB * NPIX * 4;
    int*  offs = (int*)(ws + off);    off += (size_t)NB * NVAL * 4;
    int*  cnts = (int*)(ws + off);    off += (size_t)NB * NVAL * 4;
    int*   inv = (int*)(ws + off);    off += (size_t)T_BINS * 4;

    prep<<<NB + 192 + 1, 256, 0, stream>>>(inp, pix, offs, cnts, w1, w1t, table, inv);
    compute_w<<<dim3(NVAL, NB), 256, 0, stream>>>(w1t, pix, offs, cnts, W);
    fused_dyn<<<NB, NTHREADS, 0, stream>>>(W, inv, w2, out);
}